// Round 4
// baseline (1085.540 us; speedup 1.0000x reference)
//
#include <hip/hip_runtime.h>
#include <hip/hip_bf16.h>
#include <stdint.h>

typedef __attribute__((ext_vector_type(8))) short s16x8;
typedef __attribute__((ext_vector_type(4))) short s16x4;
typedef __attribute__((ext_vector_type(4))) float f32x4;
typedef __attribute__((ext_vector_type(4))) unsigned short u16x4;
typedef __hip_bfloat16 bf16;

#define MFMA16(a, b, c) __builtin_amdgcn_mfma_f32_16x16x32_bf16((a), (b), (c), 0, 0, 0)

static __device__ __forceinline__ unsigned short bfbits(float f) {
    bf16 h = __float2bfloat16(f);
    unsigned short u;
    __builtin_memcpy(&u, &h, 2);
    return u;
}

// ---------------------------------------------------------------------------
// Weight prep: cast to bf16 and transpose to [N][K] (NT layout for all GEMMs)
// ---------------------------------------------------------------------------
__global__ void k_prep_weights(const float* __restrict__ Wq, const float* __restrict__ Wk,
                               const float* __restrict__ Wv, const float* __restrict__ Wo,
                               const float* __restrict__ W1, const float* __restrict__ W2,
                               bf16* __restrict__ wt)
{
    int idx = blockIdx.x * 256 + threadIdx.x;
    if (idx >= 1769472) return;
    float v;
    if (idx < 589824) {
        int which = idx / 147456, rem = idx % 147456;
        int n = rem / 384, kk = rem % 384;
        const float* src = (which == 0) ? Wq : (which == 1) ? Wk : (which == 2) ? Wv : Wo;
        v = src[kk * 384 + n];
    } else if (idx < 1179648) {
        int rem = idx - 589824;
        int n = rem / 384, kk = rem % 384;
        v = W1[kk * 1536 + n];
    } else {
        int rem = idx - 1179648;
        int n = rem / 1536, kk = rem % 1536;
        v = W2[kk * 384 + n];
    }
    wt[idx] = __float2bfloat16(v);
}

// ---------------------------------------------------------------------------
// LayerNorm: one wave per row of 384 f32 -> bf16. Block = 4 waves = 4 rows.
// ---------------------------------------------------------------------------
__global__ __launch_bounds__(256) void k_layernorm(const float* __restrict__ x,
                                                   const float* __restrict__ g,
                                                   const float* __restrict__ b,
                                                   bf16* __restrict__ h)
{
    int row = blockIdx.x * 4 + (threadIdx.x >> 6);
    int lane = threadIdx.x & 63;
    const float* xr = x + (size_t)row * 384;
    float v[6];
    float s = 0.f, s2 = 0.f;
#pragma unroll
    for (int j = 0; j < 6; ++j) {
        float t = xr[lane + 64 * j];
        v[j] = t; s += t; s2 += t * t;
    }
#pragma unroll
    for (int d = 32; d >= 1; d >>= 1) {
        s += __shfl_xor(s, d);
        s2 += __shfl_xor(s2, d);
    }
    float mu = s * (1.f / 384.f);
    float var = s2 * (1.f / 384.f) - mu * mu;
    float rs = rsqrtf(var + 1e-5f);
    bf16* hr = h + (size_t)row * 384;
#pragma unroll
    for (int j = 0; j < 6; ++j) {
        int c = lane + 64 * j;
        hr[c] = __float2bfloat16((v[j] - mu) * rs * g[c] + b[c]);
    }
}

// ---------------------------------------------------------------------------
// GEMM-NT: C[M,N] = A[M,K] @ Bt[N,K]^T (+bias, epilogue variants)
// 128x128 tile, BK=64, 256 threads (4 waves, 2x2 wave grid, 64x64 per wave).
// EPI: 0 = bias -> bf16
//      1 = bias + exact GELU -> bf16
//      2 = bias + residual(f32) -> f32
//      3 = bias -> bf16, output transposed per batch of 2048 rows (makes vT)
// ---------------------------------------------------------------------------
template <int EPI>
__global__ __launch_bounds__(256, 2)
void k_gemm_nt(const bf16* __restrict__ A, const bf16* __restrict__ Bt,
               const float* __restrict__ bias, const float* __restrict__ res,
               void* __restrict__ outp, int M, int N, int K)
{
    __shared__ char As[16384];
    __shared__ char Bs[16384];
    const int tid = threadIdx.x;
    const int w = tid >> 6, l = tid & 63;
    const int l15 = l & 15, lg = l >> 4;
    const int brow = blockIdx.y * 128, bcol = blockIdx.x * 128;
    const int wr = (w >> 1) * 64, wc = (w & 1) * 64;

    f32x4 acc[4][4];
#pragma unroll
    for (int i = 0; i < 4; ++i)
#pragma unroll
        for (int j = 0; j < 4; ++j) acc[i][j] = (f32x4){0.f, 0.f, 0.f, 0.f};

    const bf16* gA[4];
    const bf16* gB[4];
    int offw[4];
#pragma unroll
    for (int j = 0; j < 4; ++j) {
        int idx = j * 256 + tid;
        int row = idx >> 3, c8 = (idx & 7) << 3;
        gA[j] = A + (size_t)(brow + row) * K + c8;
        gB[j] = Bt + (size_t)(bcol + row) * K + c8;
        offw[j] = ((row << 7) | (c8 << 1)) ^ ((row & 7) << 4);
    }

    s16x8 ar[4], br[4];
#pragma unroll
    for (int j = 0; j < 4; ++j) {
        ar[j] = *reinterpret_cast<const s16x8*>(gA[j]);
        br[j] = *reinterpret_cast<const s16x8*>(gB[j]);
    }

    const int nk = K >> 6;
    for (int kt = 0; kt < nk; ++kt) {
        __syncthreads();
#pragma unroll
        for (int j = 0; j < 4; ++j) {
            *reinterpret_cast<s16x8*>(As + offw[j]) = ar[j];
            *reinterpret_cast<s16x8*>(Bs + offw[j]) = br[j];
        }
        __syncthreads();
        if (kt + 1 < nk) {
            int k0 = (kt + 1) << 6;
#pragma unroll
            for (int j = 0; j < 4; ++j) {
                ar[j] = *reinterpret_cast<const s16x8*>(gA[j] + k0);
                br[j] = *reinterpret_cast<const s16x8*>(gB[j] + k0);
            }
        }
#pragma unroll
        for (int kc = 0; kc < 2; ++kc) {
            int cb = (kc * 32 + lg * 8) << 1;
            s16x8 af[4], bfr[4];
#pragma unroll
            for (int i = 0; i < 4; ++i) {
                int rowA = wr + i * 16 + l15;
                af[i] = *reinterpret_cast<const s16x8*>(As + ((rowA << 7) | (cb ^ ((rowA & 7) << 4))));
                int rowB = wc + i * 16 + l15;
                bfr[i] = *reinterpret_cast<const s16x8*>(Bs + ((rowB << 7) | (cb ^ ((rowB & 7) << 4))));
            }
#pragma unroll
            for (int i = 0; i < 4; ++i)
#pragma unroll
                for (int j = 0; j < 4; ++j)
                    acc[i][j] = MFMA16(af[i], bfr[j], acc[i][j]);
        }
    }

#pragma unroll
    for (int i = 0; i < 4; ++i) {
#pragma unroll
        for (int j = 0; j < 4; ++j) {
            int col = bcol + wc + j * 16 + l15;
            float bi = bias[col];
            int row0 = brow + wr + i * 16 + lg * 4;
            if constexpr (EPI == 3) {
                u16x4 pk;
#pragma unroll
                for (int r = 0; r < 4; ++r) pk[r] = bfbits(acc[i][j][r] + bi);
                int batch = row0 >> 11, rloc = row0 & 2047;
                bf16* dst = (bf16*)outp + (size_t)batch * 786432 + (size_t)col * 2048 + rloc;
                *reinterpret_cast<u16x4*>(dst) = pk;
            } else {
#pragma unroll
                for (int r = 0; r < 4; ++r) {
                    int row = row0 + r;
                    float val = acc[i][j][r] + bi;
                    if constexpr (EPI == 0) {
                        ((bf16*)outp)[(size_t)row * N + col] = __float2bfloat16(val);
                    } else if constexpr (EPI == 1) {
                        float ge = 0.5f * val * (1.f + erff(val * 0.70710678118654752f));
                        ((bf16*)outp)[(size_t)row * N + col] = __float2bfloat16(ge);
                    } else {
                        ((float*)outp)[(size_t)row * N + col] = res[(size_t)row * N + col] + val;
                    }
                }
            }
        }
    }
}

// ---------------------------------------------------------------------------
// Flash attention v4: barrier-free flash-decode style.
// Block = 16 q-rows, 4 waves. Wave w independently processes kv rows
// {it*128 + w*32 .. +32} for it in 0..15, with its OWN running (m,l) and a
// full-d partial O (24 f32x4). Swapped QK^T -> in-register softmax (defer-max
// THR=8, log2 domain). P goes through a wave-private LDS patch (no barriers:
// wave-coherent lgkmcnt ordering) to become the 16x16x32 A-operand. PV reads
// vT directly (16B frags). Main loop has ZERO __syncthreads. End: 4-partial
// flash-decode combine through LDS.
// ---------------------------------------------------------------------------
__global__ __launch_bounds__(256, 2)
void k_flash_attn(const bf16* __restrict__ q, const bf16* __restrict__ k,
                  const bf16* __restrict__ vT, bf16* __restrict__ av)
{
    const int bid = blockIdx.x;
    const int batch = (bid & 7) * 2 + (bid >> 10);     // XCD-pinned: batches {2x,2x+1} on XCD x
    const int qt = (bid >> 3) & 127;
    const int q0 = qt * 16;
    const bf16* qb = q + (size_t)batch * (2048 * 384);
    const bf16* kb = k + (size_t)batch * (2048 * 384);
    const bf16* vb = vT + (size_t)batch * (384 * 2048);
    bf16* avb = av + (size_t)batch * (2048 * 384);
    const int tid = threadIdx.x, w = tid >> 6, l = tid & 63;
    const int l15 = l & 15, lg = l >> 4;

    __shared__ __align__(16) unsigned short P_w[4][16][36];  // wave-private, 72B rows
    __shared__ __align__(16) float buf[4][16][96];           // epilogue combine
    __shared__ float ml[4][2][16];

    // Q B-frags pinned: col q = l15, k-chunk kc*32 + lg*8
    s16x8 qf[12];
#pragma unroll
    for (int kc = 0; kc < 12; ++kc)
        qf[kc] = *reinterpret_cast<const s16x8*>(
            qb + (size_t)(q0 + l15) * 384 + kc * 32 + lg * 8);

    f32x4 o[24];
#pragma unroll
    for (int dn = 0; dn < 24; ++dn) o[dn] = (f32x4){0.f, 0.f, 0.f, 0.f};

    float m_run = -1e30f, l_run = 0.f;
    const float kScale = 1.4426950408889634f * 0.05103103630798288f;  // log2(e)/sqrt(384)

    for (int it = 0; it < 16; ++it) {
        const int kv0 = it * 128 + w * 32;
        const bf16* kpA = kb + (size_t)(kv0 + l15) * 384 + lg * 8;
        f32x4 st0 = (f32x4){0.f, 0.f, 0.f, 0.f};
        f32x4 st1 = (f32x4){0.f, 0.f, 0.f, 0.f};
        {
            s16x8 kf[12];
#pragma unroll
            for (int kc = 0; kc < 12; ++kc)
                kf[kc] = *reinterpret_cast<const s16x8*>(kpA + kc * 32);
            __builtin_amdgcn_s_setprio(1);
#pragma unroll
            for (int kc = 0; kc < 12; ++kc) st0 = MFMA16(kf[kc], qf[kc], st0);
            __builtin_amdgcn_s_setprio(0);
#pragma unroll
            for (int kc = 0; kc < 12; ++kc)
                kf[kc] = *reinterpret_cast<const s16x8*>(kpA + 16 * 384 + kc * 32);
            __builtin_amdgcn_s_setprio(1);
#pragma unroll
            for (int kc = 0; kc < 12; ++kc) st1 = MFMA16(kf[kc], qf[kc], st1);
            __builtin_amdgcn_s_setprio(0);
        }
        // ---- in-register online softmax (lane: q = l15; kv = lg*4+r, +16) ----
        float sv[8];
#pragma unroll
        for (int r = 0; r < 4; ++r) { sv[r] = st0[r] * kScale; sv[4 + r] = st1[r] * kScale; }
        float pmax = sv[0];
#pragma unroll
        for (int i = 1; i < 8; ++i) pmax = fmaxf(pmax, sv[i]);
        pmax = fmaxf(pmax, __shfl_xor(pmax, 16));
        pmax = fmaxf(pmax, __shfl_xor(pmax, 32));
        if (!__all(pmax <= m_run + 8.f)) {       // defer-max (T13): rescale rarely
            float mn = fmaxf(m_run, pmax);
            float f = exp2f(m_run - mn);
            m_run = mn;
            l_run *= f;
            float fq[4];
#pragma unroll
            for (int r = 0; r < 4; ++r) fq[r] = __shfl(f, lg * 4 + r);
#pragma unroll
            for (int dn = 0; dn < 24; ++dn)
#pragma unroll
                for (int r = 0; r < 4; ++r) o[dn][r] *= fq[r];
        }
        float p[8], psum = 0.f;
#pragma unroll
        for (int i = 0; i < 8; ++i) { p[i] = exp2f(sv[i] - m_run); psum += p[i]; }
        l_run += psum;                            // lg-partial; reduced at end
        // ---- P -> wave-private LDS (C-layout) -> A-frag (16B rows, no barrier)
        u16x4 pk0, pk1;
#pragma unroll
        for (int r = 0; r < 4; ++r) { pk0[r] = bfbits(p[r]); pk1[r] = bfbits(p[4 + r]); }
        *reinterpret_cast<u16x4*>(&P_w[w][l15][lg * 4]) = pk0;
        *reinterpret_cast<u16x4*>(&P_w[w][l15][16 + lg * 4]) = pk1;
        s16x4 paL = *reinterpret_cast<const s16x4*>(&P_w[w][l15][lg * 8]);
        s16x4 paH = *reinterpret_cast<const s16x4*>(&P_w[w][l15][lg * 8 + 4]);
        s16x8 pa;
#pragma unroll
        for (int i = 0; i < 4; ++i) { pa[i] = paL[i]; pa[4 + i] = paH[i]; }
        // ---- PV: o[dn] += P(16x32) x V(32x16-slice dn) ----
        const bf16* vp = vb + (size_t)l15 * 2048 + kv0 + lg * 8;
#pragma unroll
        for (int g = 0; g < 2; ++g) {
            s16x8 vf[12];
#pragma unroll
            for (int j = 0; j < 12; ++j)
                vf[j] = *reinterpret_cast<const s16x8*>(vp + (size_t)(g * 12 + j) * 32768);
            __builtin_amdgcn_s_setprio(1);
#pragma unroll
            for (int j = 0; j < 12; ++j)
                o[g * 12 + j] = MFMA16(pa, vf[j], o[g * 12 + j]);
            __builtin_amdgcn_s_setprio(0);
        }
    }

    // ---- epilogue: reduce l across lg, then 4-partial flash-decode combine
    l_run += __shfl_xor(l_run, 16);
    l_run += __shfl_xor(l_run, 32);
    if (lg == 0) { ml[w][0][l15] = m_run; ml[w][1][l15] = l_run; }

    const int qq = tid >> 4, dc = tid & 15;
#pragma unroll
    for (int ds = 0; ds < 4; ++ds) {
        __syncthreads();
#pragma unroll
        for (int j = 0; j < 6; ++j)
#pragma unroll
            for (int r = 0; r < 4; ++r)
                buf[w][lg * 4 + r][j * 16 + l15] = o[ds * 6 + j][r];
        __syncthreads();
        float m0 = ml[0][0][qq], m1 = ml[1][0][qq], m2 = ml[2][0][qq], m3 = ml[3][0][qq];
        float M = fmaxf(fmaxf(m0, m1), fmaxf(m2, m3));
        float a0 = exp2f(m0 - M), a1 = exp2f(m1 - M);
        float a2 = exp2f(m2 - M), a3 = exp2f(m3 - M);
        float den = a0 * ml[0][1][qq] + a1 * ml[1][1][qq] +
                    a2 * ml[2][1][qq] + a3 * ml[3][1][qq];
        float inv = 1.f / den;
        bf16* orow = avb + (size_t)(q0 + qq) * 384 + ds * 96;
#pragma unroll
        for (int j = 0; j < 6; ++j) {
            int c = dc + j * 16;
            float num = a0 * buf[0][qq][c] + a1 * buf[1][qq][c] +
                        a2 * buf[2][qq][c] + a3 * buf[3][qq][c];
            orow[c] = __float2bfloat16(num * inv);
        }
    }
}

// ---------------------------------------------------------------------------
// Launch: 10 kernels. ws layout as before (129.4 MB).
// ---------------------------------------------------------------------------
extern "C" void kernel_launch(void* const* d_in, const int* in_sizes, int n_in,
                              void* d_out, int out_size, void* d_ws, size_t ws_size,
                              hipStream_t stream)
{
    const float* x1 = (const float*)d_in[0];
    const float* x2 = (const float*)d_in[1];
    const float* ln1_g = (const float*)d_in[2];
    const float* ln1_b = (const float*)d_in[3];
    const float* ln2_g = (const float*)d_in[4];
    const float* ln2_b = (const float*)d_in[5];
    const float* Wq = (const float*)d_in[6];
    const float* bq = (const float*)d_in[7];
    const float* Wk = (const float*)d_in[8];
    const float* bk = (const float*)d_in[9];
    const float* Wv = (const float*)d_in[10];
    const float* bv = (const float*)d_in[11];
    const float* Wo = (const float*)d_in[12];
    const float* bo = (const float*)d_in[13];
    const float* ln3_g = (const float*)d_in[14];
    const float* ln3_b = (const float*)d_in[15];
    const float* W1 = (const float*)d_in[16];
    const float* b1 = (const float*)d_in[17];
    const float* W2 = (const float*)d_in[18];
    const float* b2 = (const float*)d_in[19];
    float* out = (float*)d_out;

    char* ws = (char*)d_ws;
    bf16* wt = (bf16*)(ws);
    bf16* qB = (bf16*)(ws + 3538944);
    bf16* kB = (bf16*)(ws + 28704768);
    bf16* vTB = (bf16*)(ws + 53870592);
    bf16* avB = (bf16*)(ws + 79036416);
    bf16* h2B = (bf16*)(ws + 104202240);
    bf16* h1B = avB;   // h1 aliases av (dead before attention output)
    bf16* h3B = h2B;   // h3 aliases h2 (dead after k/v projections)
    bf16* hhB = qB;    // hh aliases q|k|vT|av (all dead after Wo projection)

    const bf16* WqT = wt;
    const bf16* WkT = wt + 147456;
    const bf16* WvT = wt + 294912;
    const bf16* WoT = wt + 442368;
    const bf16* W1T = wt + 589824;
    const bf16* W2T = wt + 1179648;

    k_prep_weights<<<6912, 256, 0, stream>>>(Wq, Wk, Wv, Wo, W1, W2, wt);
    k_layernorm<<<8192, 256, 0, stream>>>(x1, ln1_g, ln1_b, h1B);
    k_layernorm<<<8192, 256, 0, stream>>>(x2, ln2_g, ln2_b, h2B);

    dim3 g384(3, 256), g1536(12, 256);
    k_gemm_nt<0><<<g384, 256, 0, stream>>>(h1B, WqT, bq, nullptr, qB, 32768, 384, 384);
    k_gemm_nt<0><<<g384, 256, 0, stream>>>(h2B, WkT, bk, nullptr, kB, 32768, 384, 384);
    k_gemm_nt<3><<<g384, 256, 0, stream>>>(h2B, WvT, bv, nullptr, vTB, 32768, 384, 384);

    k_flash_attn<<<2048, 256, 0, stream>>>(qB, kB, vTB, avB);

    k_gemm_nt<2><<<g384, 256, 0, stream>>>(avB, WoT, bo, x1, out, 32768, 384, 384);
    k_layernorm<<<8192, 256, 0, stream>>>(out, ln3_g, ln3_b, h3B);
    k_gemm_nt<1><<<g1536, 256, 0, stream>>>(h3B, W1T, b1, nullptr, hhB, 32768, 1536, 384);
    k_gemm_nt<2><<<g384, 256, 0, stream>>>(hhB, W2T, b2, out, out, 32768, 384, 1536);
}

// Round 6
// 570.822 us; speedup vs baseline: 1.9017x; 1.9017x over previous
//
#include <hip/hip_runtime.h>
#include <hip/hip_bf16.h>
#include <stdint.h>

typedef __attribute__((ext_vector_type(8))) short s16x8;
typedef __attribute__((ext_vector_type(4))) short s16x4;
typedef __attribute__((ext_vector_type(4))) float f32x4;
typedef __attribute__((ext_vector_type(4))) unsigned short u16x4;
typedef __hip_bfloat16 bf16;

#define AS1 __attribute__((address_space(1)))
#define AS3 __attribute__((address_space(3)))
#define MFMA16(a, b, c) __builtin_amdgcn_mfma_f32_16x16x32_bf16((a), (b), (c), 0, 0, 0)

static __device__ __forceinline__ unsigned short bfbits(float f) {
    bf16 h = __float2bfloat16(f);
    unsigned short u;
    __builtin_memcpy(&u, &h, 2);
    return u;
}

// ---------------------------------------------------------------------------
// Weight prep: cast to bf16 and transpose to [N][K] (NT layout for all GEMMs)
// ---------------------------------------------------------------------------
__global__ void k_prep_weights(const float* __restrict__ Wq, const float* __restrict__ Wk,
                               const float* __restrict__ Wv, const float* __restrict__ Wo,
                               const float* __restrict__ W1, const float* __restrict__ W2,
                               bf16* __restrict__ wt)
{
    int idx = blockIdx.x * 256 + threadIdx.x;
    if (idx >= 1769472) return;
    float v;
    if (idx < 589824) {
        int which = idx / 147456, rem = idx % 147456;
        int n = rem / 384, kk = rem % 384;
        const float* src = (which == 0) ? Wq : (which == 1) ? Wk : (which == 2) ? Wv : Wo;
        v = src[kk * 384 + n];
    } else if (idx < 1179648) {
        int rem = idx - 589824;
        int n = rem / 384, kk = rem % 384;
        v = W1[kk * 1536 + n];
    } else {
        int rem = idx - 1179648;
        int n = rem / 1536, kk = rem % 1536;
        v = W2[kk * 384 + n];
    }
    wt[idx] = __float2bfloat16(v);
}

// ---------------------------------------------------------------------------
// LayerNorm: one wave per row of 384 f32 -> bf16. Block = 4 waves = 4 rows.
// ---------------------------------------------------------------------------
__global__ __launch_bounds__(256) void k_layernorm(const float* __restrict__ x,
                                                   const float* __restrict__ g,
                                                   const float* __restrict__ b,
                                                   bf16* __restrict__ h)
{
    int row = blockIdx.x * 4 + (threadIdx.x >> 6);
    int lane = threadIdx.x & 63;
    const float* xr = x + (size_t)row * 384;
    float v[6];
    float s = 0.f, s2 = 0.f;
#pragma unroll
    for (int j = 0; j < 6; ++j) {
        float t = xr[lane + 64 * j];
        v[j] = t; s += t; s2 += t * t;
    }
#pragma unroll
    for (int d = 32; d >= 1; d >>= 1) {
        s += __shfl_xor(s, d);
        s2 += __shfl_xor(s2, d);
    }
    float mu = s * (1.f / 384.f);
    float var = s2 * (1.f / 384.f) - mu * mu;
    float rs = rsqrtf(var + 1e-5f);
    bf16* hr = h + (size_t)row * 384;
#pragma unroll
    for (int j = 0; j < 6; ++j) {
        int c = lane + 64 * j;
        hr[c] = __float2bfloat16((v[j] - mu) * rs * g[c] + b[c]);
    }
}

// ---------------------------------------------------------------------------
// GEMM-NT: C[M,N] = A[M,K] @ Bt[N,K]^T (+bias, epilogue variants)  [unchanged]
// ---------------------------------------------------------------------------
template <int EPI>
__global__ __launch_bounds__(256, 2)
void k_gemm_nt(const bf16* __restrict__ A, const bf16* __restrict__ Bt,
               const float* __restrict__ bias, const float* __restrict__ res,
               void* __restrict__ outp, int M, int N, int K)
{
    __shared__ char As[16384];
    __shared__ char Bs[16384];
    const int tid = threadIdx.x;
    const int w = tid >> 6, l = tid & 63;
    const int l15 = l & 15, lg = l >> 4;
    const int brow = blockIdx.y * 128, bcol = blockIdx.x * 128;
    const int wr = (w >> 1) * 64, wc = (w & 1) * 64;

    f32x4 acc[4][4];
#pragma unroll
    for (int i = 0; i < 4; ++i)
#pragma unroll
        for (int j = 0; j < 4; ++j) acc[i][j] = (f32x4){0.f, 0.f, 0.f, 0.f};

    const bf16* gA[4];
    const bf16* gB[4];
    int offw[4];
#pragma unroll
    for (int j = 0; j < 4; ++j) {
        int idx = j * 256 + tid;
        int row = idx >> 3, c8 = (idx & 7) << 3;
        gA[j] = A + (size_t)(brow + row) * K + c8;
        gB[j] = Bt + (size_t)(bcol + row) * K + c8;
        offw[j] = ((row << 7) | (c8 << 1)) ^ ((row & 7) << 4);
    }

    s16x8 ar[4], br[4];
#pragma unroll
    for (int j = 0; j < 4; ++j) {
        ar[j] = *reinterpret_cast<const s16x8*>(gA[j]);
        br[j] = *reinterpret_cast<const s16x8*>(gB[j]);
    }

    const int nk = K >> 6;
    for (int kt = 0; kt < nk; ++kt) {
        __syncthreads();
#pragma unroll
        for (int j = 0; j < 4; ++j) {
            *reinterpret_cast<s16x8*>(As + offw[j]) = ar[j];
            *reinterpret_cast<s16x8*>(Bs + offw[j]) = br[j];
        }
        __syncthreads();
        if (kt + 1 < nk) {
            int k0 = (kt + 1) << 6;
#pragma unroll
            for (int j = 0; j < 4; ++j) {
                ar[j] = *reinterpret_cast<const s16x8*>(gA[j] + k0);
                br[j] = *reinterpret_cast<const s16x8*>(gB[j] + k0);
            }
        }
#pragma unroll
        for (int kc = 0; kc < 2; ++kc) {
            int cb = (kc * 32 + lg * 8) << 1;
            s16x8 af[4], bfr[4];
#pragma unroll
            for (int i = 0; i < 4; ++i) {
                int rowA = wr + i * 16 + l15;
                af[i] = *reinterpret_cast<const s16x8*>(As + ((rowA << 7) | (cb ^ ((rowA & 7) << 4))));
                int rowB = wc + i * 16 + l15;
                bfr[i] = *reinterpret_cast<const s16x8*>(Bs + ((rowB << 7) | (cb ^ ((rowB & 7) << 4))));
            }
#pragma unroll
            for (int i = 0; i < 4; ++i)
#pragma unroll
                for (int j = 0; j < 4; ++j)
                    acc[i][j] = MFMA16(af[i], bfr[j], acc[i][j]);
        }
    }

#pragma unroll
    for (int i = 0; i < 4; ++i) {
#pragma unroll
        for (int j = 0; j < 4; ++j) {
            int col = bcol + wc + j * 16 + l15;
            float bi = bias[col];
            int row0 = brow + wr + i * 16 + lg * 4;
            if constexpr (EPI == 3) {
                u16x4 pk;
#pragma unroll
                for (int r = 0; r < 4; ++r) pk[r] = bfbits(acc[i][j][r] + bi);
                int batch = row0 >> 11, rloc = row0 & 2047;
                bf16* dst = (bf16*)outp + (size_t)batch * 786432 + (size_t)col * 2048 + rloc;
                *reinterpret_cast<u16x4*>(dst) = pk;
            } else {
#pragma unroll
                for (int r = 0; r < 4; ++r) {
                    int row = row0 + r;
                    float val = acc[i][j][r] + bi;
                    if constexpr (EPI == 0) {
                        ((bf16*)outp)[(size_t)row * N + col] = __float2bfloat16(val);
                    } else if constexpr (EPI == 1) {
                        float ge = 0.5f * val * (1.f + erff(val * 0.70710678118654752f));
                        ((bf16*)outp)[(size_t)row * N + col] = __float2bfloat16(ge);
                    } else {
                        ((float*)outp)[(size_t)row * N + col] = res[(size_t)row * N + col] + val;
                    }
                }
            }
        }
    }
}

// ---------------------------------------------------------------------------
// Flash attention v6: GEMM-style LDS staging + wave-independent compute.
// Block = 512 threads (8 waves), q-tile 128: wave w owns q rows [q0+16w,+16)
// completely (in-register online softmax, full-d O accumulator o[24]).
// Per iter (kv-tile 32): K tile (32x768B) and vT tile (384x64B) staged into
// double-buffered LDS via global_load_lds (16B), with pre-swizzled per-lane
// SOURCES (linear LDS dest) and swizzled reads:
//   K: byte ^= ((row&7)<<4)   (row = kv)   -> matches verified GEMM pattern
//   V: byte ^= (((row&3)^((row>>2)&1))<<4) (row = d)
// One __syncthreads per iter (drains stage vmcnt + fences buffer reuse).
// XCD pinning: batch = bid&15 arranged so a batch's 16 blocks share an XCD.
// ---------------------------------------------------------------------------
__global__ __launch_bounds__(512, 2)
void k_flash_attn(const bf16* __restrict__ q, const bf16* __restrict__ k,
                  const bf16* __restrict__ vT, bf16* __restrict__ av)
{
    const int bid = blockIdx.x;
    const int batch = (bid & 7) + 8 * ((bid >> 3) & 1);
    const int q0 = (bid >> 4) * 128;
    const bf16* qb = q + (size_t)batch * (2048 * 384);
    const bf16* kb = k + (size_t)batch * (2048 * 384);
    const bf16* vb = vT + (size_t)batch * (384 * 2048);
    bf16* avb = av + (size_t)batch * (2048 * 384);
    const int tid = threadIdx.x, w = tid >> 6, l = tid & 63;
    const int l15 = l & 15, lg = l >> 4;

    __shared__ __align__(16) char Kl[2][24576];              // [32 kv][768B], swizzled
    __shared__ __align__(16) char Vl[2][24576];              // [384 d][64B], swizzled
    __shared__ __align__(16) unsigned short P_w[8][16][36];  // wave-private P patch

    // staging source offsets (pre-swizzled so linear LDS + swizzled read works)
    int kSrc[3], vSrc[3];
#pragma unroll
    for (int j = 0; j < 3; ++j) {
        int o = j * 8192 + tid * 16;
        int kr = o / 768, kcb = o - kr * 768;
        kSrc[j] = kr * 768 + (kcb ^ ((kr & 7) << 4));
        int vr = o >> 6, vcb = o & 63;
        vSrc[j] = vr * 4096 + (vcb ^ ((((vr & 3) ^ ((vr >> 2) & 1))) << 4));
    }
    const char* kbyte = (const char*)kb;
    const char* vbyte = (const char*)vb;

    // prologue: stage tile 0 into buffer 0
#pragma unroll
    for (int j = 0; j < 3; ++j) {
        __builtin_amdgcn_global_load_lds(
            (const AS1 void*)(kbyte + kSrc[j]),
            (AS3 void*)(&Kl[0][j * 8192 + w * 1024]), 16, 0, 0);
        __builtin_amdgcn_global_load_lds(
            (const AS1 void*)(vbyte + vSrc[j]),
            (AS3 void*)(&Vl[0][j * 8192 + w * 1024]), 16, 0, 0);
    }

    // Q B-frags pinned in registers: col q = l15, k-chunk kc*32 + lg*8
    s16x8 qf[12];
#pragma unroll
    for (int kc = 0; kc < 12; ++kc)
        qf[kc] = *reinterpret_cast<const s16x8*>(
            qb + (size_t)(q0 + w * 16 + l15) * 384 + kc * 32 + lg * 8);

    f32x4 o[24];
#pragma unroll
    for (int dn = 0; dn < 24; ++dn) o[dn] = (f32x4){0.f, 0.f, 0.f, 0.f};

    float m_run = -1e30f, l_run = 0.f;
    const float kScale = 1.4426950408889634f * 0.05103103630798288f;  // log2(e)/sqrt(384)
    const int kswz = (l15 & 7) << 4;
    const int vswz = ((l15 & 3) ^ ((l15 >> 2) & 1)) << 4;

    __syncthreads();

    for (int t = 0; t < 64; ++t) {
        const int cur = t & 1;
        if (t + 1 < 64) {
            const size_t kvK = (size_t)(t + 1) * 32 * 768;
            const size_t kvV = (size_t)(t + 1) * 32 * 2;
#pragma unroll
            for (int j = 0; j < 3; ++j) {
                __builtin_amdgcn_global_load_lds(
                    (const AS1 void*)(kbyte + kvK + kSrc[j]),
                    (AS3 void*)(&Kl[cur ^ 1][j * 8192 + w * 1024]), 16, 0, 0);
                __builtin_amdgcn_global_load_lds(
                    (const AS1 void*)(vbyte + kvV + vSrc[j]),
                    (AS3 void*)(&Vl[cur ^ 1][j * 8192 + w * 1024]), 16, 0, 0);
            }
        }
        const char* Kb = Kl[cur];
        const char* Vb = Vl[cur];

        // ---- QK^T (swapped): lane holds S^T[kv = lg*4+r (+16)][q = l15]
        f32x4 s0a = (f32x4){0.f, 0.f, 0.f, 0.f}, s0b = s0a, s1a = s0a, s1b = s0a;
        __builtin_amdgcn_s_setprio(1);
#pragma unroll
        for (int kc = 0; kc < 6; ++kc) {
            s16x8 kf0 = *reinterpret_cast<const s16x8*>(Kb + l15 * 768 + ((kc * 64 + lg * 16) ^ kswz));
            s16x8 kf1 = *reinterpret_cast<const s16x8*>(Kb + (16 + l15) * 768 + ((kc * 64 + lg * 16) ^ kswz));
            s0a = MFMA16(kf0, qf[kc], s0a);
            s1a = MFMA16(kf1, qf[kc], s1a);
        }
#pragma unroll
        for (int kc = 6; kc < 12; ++kc) {
            s16x8 kf0 = *reinterpret_cast<const s16x8*>(Kb + l15 * 768 + ((kc * 64 + lg * 16) ^ kswz));
            s16x8 kf1 = *reinterpret_cast<const s16x8*>(Kb + (16 + l15) * 768 + ((kc * 64 + lg * 16) ^ kswz));
            s0b = MFMA16(kf0, qf[kc], s0b);
            s1b = MFMA16(kf1, qf[kc], s1b);
        }
        __builtin_amdgcn_s_setprio(0);
        f32x4 st0 = s0a + s0b, st1 = s1a + s1b;

        // ---- in-register online softmax (q = l15) ----
        float sv[8];
#pragma unroll
        for (int r = 0; r < 4; ++r) { sv[r] = st0[r] * kScale; sv[4 + r] = st1[r] * kScale; }
        float pmax = sv[0];
#pragma unroll
        for (int i = 1; i < 8; ++i) pmax = fmaxf(pmax, sv[i]);
        pmax = fmaxf(pmax, __shfl_xor(pmax, 16));
        pmax = fmaxf(pmax, __shfl_xor(pmax, 32));
        if (!__all(pmax <= m_run + 8.f)) {       // defer-max (T13)
            float mn = fmaxf(m_run, pmax);
            float f = exp2f(m_run - mn);
            m_run = mn;
            l_run *= f;
            float fq[4];
#pragma unroll
            for (int r = 0; r < 4; ++r) fq[r] = __shfl(f, lg * 4 + r);
#pragma unroll
            for (int dn = 0; dn < 24; ++dn)
#pragma unroll
                for (int r = 0; r < 4; ++r) o[dn][r] *= fq[r];
        }
        float p[8], psum = 0.f;
#pragma unroll
        for (int i = 0; i < 8; ++i) { p[i] = exp2f(sv[i] - m_run); psum += p[i]; }
        l_run += psum;

        // ---- P -> wave-private LDS (C-layout) -> A-frag (no barrier) ----
        u16x4 pk0, pk1;
#pragma unroll
        for (int r = 0; r < 4; ++r) { pk0[r] = bfbits(p[r]); pk1[r] = bfbits(p[4 + r]); }
        *reinterpret_cast<u16x4*>(&P_w[w][l15][lg * 4]) = pk0;
        *reinterpret_cast<u16x4*>(&P_w[w][l15][16 + lg * 4]) = pk1;
        s16x4 paL = *reinterpret_cast<const s16x4*>(&P_w[w][l15][lg * 8]);
        s16x4 paH = *reinterpret_cast<const s16x4*>(&P_w[w][l15][lg * 8 + 4]);
        s16x8 pa;
#pragma unroll
        for (int i = 0; i < 4; ++i) { pa[i] = paL[i]; pa[4 + i] = paH[i]; }

        // ---- PV: o[dn] += P(16x32) x V(32 x 16-col slice dn) ----
        __builtin_amdgcn_s_setprio(1);
#pragma unroll
        for (int dn = 0; dn < 24; ++dn) {
            s16x8 vf = *reinterpret_cast<const s16x8*>(
                Vb + (dn * 16 + l15) * 64 + ((lg * 16) ^ vswz));
            o[dn] = MFMA16(pa, vf, o[dn]);
        }
        __builtin_amdgcn_s_setprio(0);

        __syncthreads();  // drains stage vmcnt + fences buffer reuse
    }

    // ---- epilogue: av = O / l  (each wave owns its 16 q rows fully) ----
    l_run += __shfl_xor(l_run, 16);
    l_run += __shfl_xor(l_run, 32);
    float inv = 1.f / l_run;
    float invr[4];
#pragma unroll
    for (int r = 0; r < 4; ++r) invr[r] = __shfl(inv, lg * 4 + r);
    bf16* outb = avb + (size_t)(q0 + w * 16) * 384;
#pragma unroll
    for (int dn = 0; dn < 24; ++dn)
#pragma unroll
        for (int r = 0; r < 4; ++r)
            outb[(size_t)(lg * 4 + r) * 384 + dn * 16 + l15] =
                __float2bfloat16(o[dn][r] * invr[r]);
}

// ---------------------------------------------------------------------------
// Launch: 10 kernels. ws layout as before (129.4 MB).
// ---------------------------------------------------------------------------
extern "C" void kernel_launch(void* const* d_in, const int* in_sizes, int n_in,
                              void* d_out, int out_size, void* d_ws, size_t ws_size,
                              hipStream_t stream)
{
    const float* x1 = (const float*)d_in[0];
    const float* x2 = (const float*)d_in[1];
    const float* ln1_g = (const float*)d_in[2];
    const float* ln1_b = (const float*)d_in[3];
    const float* ln2_g = (const float*)d_in[4];
    const float* ln2_b = (const float*)d_in[5];
    const float* Wq = (const float*)d_in[6];
    const float* bq = (const float*)d_in[7];
    const float* Wk = (const float*)d_in[8];
    const float* bk = (const float*)d_in[9];
    const float* Wv = (const float*)d_in[10];
    const float* bv = (const float*)d_in[11];
    const float* Wo = (const float*)d_in[12];
    const float* bo = (const float*)d_in[13];
    const float* ln3_g = (const float*)d_in[14];
    const float* ln3_b = (const float*)d_in[15];
    const float* W1 = (const float*)d_in[16];
    const float* b1 = (const float*)d_in[17];
    const float* W2 = (const float*)d_in[18];
    const float* b2 = (const float*)d_in[19];
    float* out = (float*)d_out;

    char* ws = (char*)d_ws;
    bf16* wt = (bf16*)(ws);
    bf16* qB = (bf16*)(ws + 3538944);
    bf16* kB = (bf16*)(ws + 28704768);
    bf16* vTB = (bf16*)(ws + 53870592);
    bf16* avB = (bf16*)(ws + 79036416);
    bf16* h2B = (bf16*)(ws + 104202240);
    bf16* h1B = avB;   // h1 aliases av (dead before attention output)
    bf16* h3B = h2B;   // h3 aliases h2 (dead after k/v projections)
    bf16* hhB = qB;    // hh aliases q|k|vT|av (all dead after Wo projection)

    const bf16* WqT = wt;
    const bf16* WkT = wt + 147456;
    const bf16* WvT = wt + 294912;
    const bf16* WoT = wt + 442368;
    const bf16* W1T = wt + 589824;
    const bf16* W2T = wt + 1179648;

    k_prep_weights<<<6912, 256, 0, stream>>>(Wq, Wk, Wv, Wo, W1, W2, wt);
    k_layernorm<<<8192, 256, 0, stream>>>(x1, ln1_g, ln1_b, h1B);
    k_layernorm<<<8192, 256, 0, stream>>>(x2, ln2_g, ln2_b, h2B);

    dim3 g384(3, 256), g1536(12, 256);
    k_gemm_nt<0><<<g384, 256, 0, stream>>>(h1B, WqT, bq, nullptr, qB, 32768, 384, 384);
    k_gemm_nt<0><<<g384, 256, 0, stream>>>(h2B, WkT, bk, nullptr, kB, 32768, 384, 384);
    k_gemm_nt<3><<<g384, 256, 0, stream>>>(h2B, WvT, bv, nullptr, vTB, 32768, 384, 384);

    k_flash_attn<<<256, 512, 0, stream>>>(qB, kB, vTB, avB);

    k_gemm_nt<2><<<g384, 256, 0, stream>>>(avB, WoT, bo, x1, out, 32768, 384, 384);
    k_layernorm<<<8192, 256, 0, stream>>>(out, ln3_g, ln3_b, h3B);
    k_gemm_nt<1><<<g1536, 256, 0, stream>>>(h3B, W1T, b1, nullptr, hhB, 32768, 1536, 384);
    k_gemm_nt<2><<<g384, 256, 0, stream>>>(hhB, W2T, b2, out, out, 32768, 384, 1536);
}